// Round 10
// baseline (79.828 us; speedup 1.0000x reference)
//
#include <hip/hip_runtime.h>
#include <stdint.h>

typedef __attribute__((ext_vector_type(4))) float f32x4;
typedef __attribute__((ext_vector_type(2))) unsigned int u32x2;

#define NROW 4096
#define DDIM 512
#define NT   33            // tiles per dim (128 each)
#define TS   128
#define NPAD 4224

// ---------------- ws layout (bytes) ----------------
#define WB_OFF   0u          // fp8[4224*512] = 2162688
#define GB_OFF   2162688u    // fp8[4224*512]
#define SQBW_OFF 4325376u    // float[4224]
#define SQBG_OFF 4342272u    // float[4224]
#define SCS_OFF  4359168u    // float[32][512] (zeroed)
#define SSP_OFF  4424704u    // double[256]    (zeroed)
#define PU_OFF   4426752u    // float[33][33][128] = 557568 (fully written)
#define PV_OFF   4984320u    // float[33][33][128]
#define PSL_OFF  5541888u    // double[561]    (fully written)
#define ZERO_BEG SCS_OFF
#define ZERO_END (SSP_OFF + 2048u)

__device__ __forceinline__ void atomAddF64(double* p, double v) {
  __hip_atomic_fetch_add(p, v, __ATOMIC_RELAXED, __HIP_MEMORY_SCOPE_AGENT);
}
__device__ __forceinline__ void atomAddF32(float* p, float v) {
  __hip_atomic_fetch_add(p, v, __ATOMIC_RELAXED, __HIP_MEMORY_SCOPE_AGENT);
}

// ---- fp8 e4m3fn helpers ----
__device__ __forceinline__ float fp8dec(unsigned b) {
  unsigned e = (b >> 3) & 15u, m = b & 7u;
  float v = ldexpf((float)(e ? (m | 8u) : m), (int)e - 10 + (e == 0));
  return (b & 0x80u) ? -v : v;
}

__device__ __forceinline__ unsigned f2fp8_manual(float f) {
  unsigned u = __float_as_uint(f);
  unsigned s = (u >> 24) & 0x80u;
  float a = __uint_as_float(u & 0x7FFFFFFFu);
  if (a >= 448.f) return s | 0x7Eu;
  if (a >= 0.015625f) {
    unsigned au = __float_as_uint(a);
    au += 0x7FFFFu + ((au >> 20) & 1u);
    unsigned e = (au >> 23) - 120u;
    unsigned m = (au >> 20) & 7u;
    if (e >= 16u) return s | 0x7Eu;
    return s | (e << 3) | m;
  }
  int q = (int)rintf(a * 512.f);
  return s | (unsigned)q;
}

#if __has_builtin(__builtin_amdgcn_cvt_pk_fp8_f32)
__device__ __forceinline__ unsigned pack4_fp8(float x0, float x1, float x2, float x3) {
  unsigned p = __builtin_amdgcn_cvt_pk_fp8_f32(x0, x1, 0, false);
  p = __builtin_amdgcn_cvt_pk_fp8_f32(x2, x3, p, true);
  return p;
}
#else
__device__ __forceinline__ unsigned pack4_fp8(float x0, float x1, float x2, float x3) {
  return f2fp8_manual(x0) | (f2fp8_manual(x1) << 8) |
         (f2fp8_manual(x2) << 16) | (f2fp8_manual(x3) << 24);
}
#endif

__device__ __forceinline__ void gload16(const void* g, void* l) {
  __builtin_amdgcn_global_load_lds(
      (const __attribute__((address_space(1))) unsigned int*)g,
      (__attribute__((address_space(3))) unsigned int*)l, 16, 0, 0);
}

// ---- prep: 16 rows/block; fp32->fp8, fp8-consistent row sumsq, register col sums
__global__ __launch_bounds__(256) void prep_rows(
    const float* __restrict__ W, const float* __restrict__ G,
    unsigned char* __restrict__ Wb, unsigned char* __restrict__ Gb,
    float* __restrict__ sqbW, float* __restrict__ sqbG,
    double* __restrict__ ssp, float* __restrict__ scs)
{
  __shared__ float colsLDS[4][512];
  const int bid = blockIdx.x;
  const int w = threadIdx.x >> 6;
  const int l = threadIdx.x & 63;

  if (bid >= 512) {                          // pad-row zeroing: 16 blocks x 16 rows
    #pragma unroll
    for (int it = 0; it < 4; ++it) {
      const int pr = (bid - 512) * 16 + it * 4 + w;   // 0..255
      const bool isG = pr >= 128;
      const int row = NROW + (pr & 127);
      unsigned char* dst = (isG ? Gb : Wb) + (size_t)row * DDIM;
      *(u32x2*)(dst + l * 8) = (u32x2){0u, 0u};
      if (l == 0) (isG ? sqbG : sqbW)[row] = 0.f;
    }
    return;
  }

  float colr[8] = {0.f,0.f,0.f,0.f,0.f,0.f,0.f,0.f};
  float s32 = 0.f;

  #pragma unroll
  for (int it = 0; it < 4; ++it) {
    const int row = bid * 16 + it * 4 + w;   // 0..8191
    const float* src; unsigned char* dst; float* sqb; int r;
    if (row < NROW) { src = W + (size_t)row * DDIM; dst = Wb + (size_t)row * DDIM; sqb = sqbW; r = row; }
    else            { src = G + (size_t)(row - NROW) * DDIM; dst = Gb + (size_t)(row - NROW) * DDIM; sqb = sqbG; r = row - NROW; }
    const f32x4 a = *(const f32x4*)(src + l * 8);
    const f32x4 b = *(const f32x4*)(src + l * 8 + 4);
    const unsigned p0 = pack4_fp8(a[0], a[1], a[2], a[3]);
    const unsigned p1 = pack4_fp8(b[0], b[1], b[2], b[3]);
    *(u32x2*)(dst + l * 8) = (u32x2){p0, p1};

    float sb = 0.f;
    #pragma unroll
    for (int j = 0; j < 4; ++j) {
      s32 += a[j] * a[j] + b[j] * b[j];
      colr[j] += a[j]; colr[4 + j] += b[j];
      float xa = fp8dec((p0 >> (8 * j)) & 0xFFu);
      float xb = fp8dec((p1 >> (8 * j)) & 0xFFu);
      sb += xa * xa + xb * xb;
    }
    #pragma unroll
    for (int off = 32; off > 0; off >>= 1) sb += __shfl_down(sb, off);
    if (l == 0) sqb[r] = sb;
  }

  // col partials: one LDS write per thread, 512 f32 atomics per block (4x fewer)
  #pragma unroll
  for (int j = 0; j < 8; ++j) colsLDS[w][l * 8 + j] = colr[j];
  __syncthreads();
  {
    const int c = threadIdx.x;
    atomAddF32(&scs[(bid & 31) * 512 + c],
               colsLDS[0][c] + colsLDS[1][c] + colsLDS[2][c] + colsLDS[3][c]);
    const int c2 = c + 256;
    atomAddF32(&scs[(bid & 31) * 512 + c2],
               colsLDS[0][c2] + colsLDS[1][c2] + colsLDS[2][c2] + colsLDS[3][c2]);
  }
  #pragma unroll
  for (int off = 32; off > 0; off >>= 1) s32 += __shfl_down(s32, off);
  if (l == 0) atomAddF64(&ssp[bid & 255], (double)s32);
}

// ---- stage one BK=64 step: 4 fp8 panels AW|BW|AG|BG (128x64B = 8KB each, 32KB)
// linear LDS dest; source 16B-slot pre-swizzled j16 ^ ((row>>1)&3) (rule #21)
__device__ __forceinline__ void stage_step(
    const unsigned char* __restrict__ Wb, const unsigned char* __restrict__ Gb,
    int i0, int j0, int st, int tid, unsigned char* __restrict__ buf)
{
  #pragma unroll
  for (int q = 0; q < 8; ++q) {
    const int slot = q * 256 + tid;     // 0..2047, 16B each; 512 slots per panel
    const int p = slot >> 9;
    const unsigned char* mat = (p < 2) ? Wb : Gb;
    const int rb = (p & 1) ? j0 : i0;
    const int r = slot & 511;
    const int row = r >> 2;
    const int src = (r & 3) ^ ((row >> 1) & 3);
    gload16(mat + (size_t)(rb + row) * 512 + st * 64 + src * 16, buf + slot * 16);
  }
}

// ---- one K=64 step (2 x K=32 MFMA) for one gram; read XOR j8^(row&6): <=2-way banks
__device__ __forceinline__ void gram_pass(
    const unsigned char* __restrict__ A, const unsigned char* __restrict__ B,
    int wr, int wc, int lr, int g, f32x4 acc[4][4])
{
  #pragma unroll
  for (int kk = 0; kk < 2; ++kk) {
    long long a[4], b[4];
    const int j8 = kk * 4 + g;
    #pragma unroll
    for (int m = 0; m < 4; ++m) {
      const int row = wr * 64 + m * 16 + lr;
      a[m] = *(const long long*)(A + row * 64 + ((j8 ^ (row & 6)) << 3));
    }
    #pragma unroll
    for (int n = 0; n < 4; ++n) {
      const int row = wc * 64 + n * 16 + lr;
      b[n] = *(const long long*)(B + row * 64 + ((j8 ^ (row & 6)) << 3));
    }
    __builtin_amdgcn_s_setprio(1);
    #pragma unroll
    for (int m = 0; m < 4; ++m)
      #pragma unroll
      for (int n = 0; n < 4; ++n)
        acc[m][n] = __builtin_amdgcn_mfma_f32_16x16x32_fp8_fp8(a[m], b[n], acc[m][n], 0, 0, 0);
    __builtin_amdgcn_s_setprio(0);
  }
}

// ---- main: 128^2 upper-tri tiles, 561 blocks (~2.2/CU for cross-block overlap)
__global__ __launch_bounds__(256, 2) void gram_kernel(
    const unsigned char* __restrict__ Wb, const unsigned char* __restrict__ Gb,
    const float* __restrict__ sqbW, const float* __restrict__ sqbG,
    const float* __restrict__ scs, const double* __restrict__ ssp,
    float* __restrict__ PU, float* __restrict__ PV, double* __restrict__ PSL)
{
  __shared__ __align__(16) unsigned char lds[32768];   // AW|BW|AG|BG, 8KB each
  __shared__ float L[512];   // rowW|rowG|colW|colG
  __shared__ double pred[4], pred2[4];
  __shared__ float sS4;

  // T1: bijective XCD-chunked swizzle (nwg=561: q=70, r=1)
  const int orig = blockIdx.x;
  const int xcd = orig & 7;
  const int idx = orig >> 3;
  const int swz = (xcd == 0 ? 0 : 71 + (xcd - 1) * 70) + idx;

  // decode upper-triangular tile: 0 <= bi <= bj < 33
  int t = swz;
  int bi = 0;
  while (t >= NT - bi) { t -= NT - bi; ++bi; }
  const int bj = bi + t;
  const bool offdiag = (bi != bj);

  const int tid = threadIdx.x;
  const int lane = tid & 63;
  const int wid = tid >> 6;
  const int wr = wid >> 1;      // 0..1
  const int wc = wid & 1;       // 0..1
  const int i0 = bi * TS;
  const int j0 = bj * TS;
  const int g = lane >> 4;
  const int lr = lane & 15;

  f32x4 accW[4][4], accG[4][4];
  #pragma unroll
  for (int m = 0; m < 4; ++m)
    #pragma unroll
    for (int n = 0; n < 4; ++n) { accW[m][n] = (f32x4)0.0f; accG[m][n] = (f32x4)0.0f; }

  for (int st = 0; st < 8; ++st) {
    stage_step(Wb, Gb, i0, j0, st, tid, lds);
    __syncthreads();
    gram_pass(lds, lds + 8192, wr, wc, lr, g, accW);
    gram_pass(lds + 16384, lds + 24576, wr, wc, lr, g, accG);
    __syncthreads();
  }

  // ---- folded bwk ----
  {
    float cs1 = 0.f, cs2 = 0.f;
    #pragma unroll 8
    for (int p = 0; p < 32; ++p) { cs1 += scs[p * 512 + tid]; cs2 += scs[p * 512 + tid + 256]; }
    double p1 = (double)cs1 * (double)cs1 + (double)cs2 * (double)cs2;
    double p2 = ssp[tid];
    #pragma unroll
    for (int off = 32; off > 0; off >>= 1) {
      p1 += __shfl_xor(p1, off);
      p2 += __shfl_xor(p2, off);
    }
    if (lane == 0) { pred[wid] = p1; pred2[wid] = p2; }
    __syncthreads();
    if (tid == 0) {
      double s2 = pred[0] + pred[1] + pred[2] + pred[3];
      double ss = pred2[0] + pred2[1] + pred2[2] + pred2[3];
      double sum_d2 = 2.0 * 8192.0 * ss - 2.0 * s2;
      double bw = sum_d2 / (8192.0 * 8191.0) / 4.0;
      sS4 = (float)(1.4426950408889634 / (bw * 16.0));
    }
    __syncthreads();
  }
  const float s4 = sS4;

  // zero ALL 512 reduction slots (256 threads, two passes)
  L[tid] = 0.f;
  L[256 + tid] = 0.f;

  // ---- epilogue: kernel values in registers ----
  float rjW[4], rjG[4], mjf[4];
  #pragma unroll
  for (int n = 0; n < 4; ++n) {
    const int j = j0 + wc * 64 + n * 16 + lr;
    rjW[n] = sqbW[j]; rjG[n] = sqbG[j];
    mjf[n] = (j < NROW) ? 1.f : 0.f;
  }

  float csW[4] = {0.f,0.f,0.f,0.f}, csG[4] = {0.f,0.f,0.f,0.f};
  float rsW[4][4], rsG[4][4];
  double p_loc = 0.0;

  #pragma unroll
  for (int m = 0; m < 4; ++m) {
    const int ib = i0 + wr * 64 + m * 16 + g * 4;
    float riW[4], riG[4], mif[4];
    #pragma unroll
    for (int e = 0; e < 4; ++e) {
      riW[e] = sqbW[ib + e]; riG[e] = sqbG[ib + e];
      mif[e] = (ib + e < NROW) ? 1.f : 0.f;
    }
    #pragma unroll
    for (int e = 0; e < 4; ++e) { rsW[m][e] = 0.f; rsG[m][e] = 0.f; }
    #pragma unroll
    for (int n = 0; n < 4; ++n) {
      #pragma unroll
      for (int e = 0; e < 4; ++e) {
        const float mk = mif[e] * mjf[n];
        float d2w = fmaxf(riW[e] + rjW[n] - 2.f * accW[m][n][e], 0.f);
        float yw = exp2f(-d2w * s4);
        float yw2 = yw * yw, yw4 = yw2 * yw2, yw8 = yw4 * yw4, yw16 = yw8 * yw8;
        float kw = (yw + yw2 + yw4 + yw8 + yw16) * mk;
        float d2g = fmaxf(riG[e] + rjG[n] - 2.f * accG[m][n][e], 0.f);
        float yg = exp2f(-d2g * s4);
        float yg2 = yg * yg, yg4 = yg2 * yg2, yg8 = yg4 * yg4, yg16 = yg8 * yg8;
        float kg = (yg + yg2 + yg4 + yg8 + yg16) * mk;
        p_loc += (double)(kw * kg);
        rsW[m][e] += kw; rsG[m][e] += kg;
        csW[n] += kw; csG[n] += kg;
      }
    }
  }

  __syncthreads();   // L zeroing visible

  // row sums -> LDS
  #pragma unroll
  for (int m = 0; m < 4; ++m)
    #pragma unroll
    for (int e = 0; e < 4; ++e) {
      float x = rsW[m][e], y = rsG[m][e];
      x += __shfl_xor(x, 1); x += __shfl_xor(x, 2); x += __shfl_xor(x, 4); x += __shfl_xor(x, 8);
      y += __shfl_xor(y, 1); y += __shfl_xor(y, 2); y += __shfl_xor(y, 4); y += __shfl_xor(y, 8);
      if (lr == 0) {
        const int rloc = wr * 64 + m * 16 + g * 4 + e;   // 0..127
        atomicAdd(&L[rloc], x);
        atomicAdd(&L[128 + rloc], y);
      }
    }

  // col sums -> LDS (transposed half, K symmetric)
  if (offdiag) {
    #pragma unroll
    for (int n = 0; n < 4; ++n) {
      float x = csW[n], y = csG[n];
      x += __shfl_xor(x, 16); x += __shfl_xor(x, 32);
      y += __shfl_xor(y, 16); y += __shfl_xor(y, 32);
      if (g == 0) {
        const int cloc = wc * 64 + n * 16 + lr;          // 0..127
        atomicAdd(&L[256 + cloc], x);
        atomicAdd(&L[384 + cloc], y);
      }
    }
  }

  __syncthreads();

  // plain coalesced partial stores (no global atomics)
  if (tid < 128) {
    PU[(bi * NT + bj) * 128 + tid] = L[tid];
    PV[(bi * NT + bj) * 128 + tid] = L[128 + tid];
    if (offdiag) {
      PU[(bj * NT + bi) * 128 + tid] = L[256 + tid];
      PV[(bj * NT + bi) * 128 + tid] = L[384 + tid];
    }
  }

  // P: wave butterfly, block sum, one plain f64 store per tile
  #pragma unroll
  for (int off = 32; off > 0; off >>= 1) p_loc += __shfl_xor(p_loc, off);
  if (lane == 0) pred[wid] = p_loc;
  __syncthreads();
  if (tid == 0) {
    double ps = pred[0] + pred[1] + pred[2] + pred[3];
    PSL[swz] = offdiag ? 2.0 * ps : ps;
  }
}

// ---- finalize: u,v from partials; loss
__global__ __launch_bounds__(1024) void finalize(
    const float* __restrict__ PU, const float* __restrict__ PV,
    const double* __restrict__ PSL, float* __restrict__ out)
{
  __shared__ double r0[1024], r1[1024], r2[1024], r3[1024];
  const int t = threadIdx.x;
  double uv = 0.0, su = 0.0, sv = 0.0, pp = 0.0;
  for (int i = t; i < NPAD; i += 1024) {
    const int b = i >> 7, ii = i & 127;
    double uu = 0.0, vv = 0.0;
    #pragma unroll
    for (int k = 0; k < NT; ++k) {
      uu += (double)PU[(b * NT + k) * 128 + ii];
      vv += (double)PV[(b * NT + k) * 128 + ii];
    }
    uv += uu * vv; su += uu; sv += vv;
  }
  if (t < 561) pp = PSL[t];
  r0[t] = uv; r1[t] = su; r2[t] = sv; r3[t] = pp;
  __syncthreads();
  for (int k = 512; k > 0; k >>= 1) {
    if (t < k) { r0[t] += r0[t + k]; r1[t] += r1[t + k]; r2[t] += r2[t + k]; r3[t] += r3[t + k]; }
    __syncthreads();
  }
  if (t == 0) {
    const double n = 4096.0;
    double hsic = r3[0] - (2.0 / n) * r0[0] + (r1[0] * r2[0]) / (n * n);
    out[0] = (float)(-hsic / ((n - 1.0) * (n - 1.0)));
  }
}

extern "C" void kernel_launch(void* const* d_in, const int* in_sizes, int n_in,
                              void* d_out, int out_size, void* d_ws, size_t ws_size,
                              hipStream_t stream) {
  const float* W = (const float*)d_in[0];
  const float* G = (const float*)d_in[1];
  char* ws = (char*)d_ws;
  unsigned char* Wb = (unsigned char*)(ws + WB_OFF);
  unsigned char* Gb = (unsigned char*)(ws + GB_OFF);
  float* sqbW = (float*)(ws + SQBW_OFF);
  float* sqbG = (float*)(ws + SQBG_OFF);
  float* scs = (float*)(ws + SCS_OFF);
  double* ssp = (double*)(ws + SSP_OFF);
  float* PU = (float*)(ws + PU_OFF);
  float* PV = (float*)(ws + PV_OFF);
  double* PSL = (double*)(ws + PSL_OFF);

  hipMemsetAsync(ws + ZERO_BEG, 0, ZERO_END - ZERO_BEG, stream);

  prep_rows<<<528, 256, 0, stream>>>(W, G, Wb, Gb, sqbW, sqbG, ssp, scs);
  gram_kernel<<<561, 256, 0, stream>>>(Wb, Gb, sqbW, sqbG, scs, ssp, PU, PV, PSL);
  finalize<<<1, 1024, 0, stream>>>(PU, PV, PSL, (float*)d_out);
}

// Round 11
// 72.359 us; speedup vs baseline: 1.1032x; 1.1032x over previous
//
#include <hip/hip_runtime.h>
#include <stdint.h>

typedef __attribute__((ext_vector_type(4))) float f32x4;
typedef __attribute__((ext_vector_type(2))) unsigned int u32x2;

#define NROW 4096
#define DDIM 512
#define NT   33            // tiles per dim (128 each)
#define TS   128
#define NPAD 4224

// ---------------- ws layout (bytes) ----------------
#define WB_OFF   0u          // fp8[4224*512] = 2162688
#define GB_OFF   2162688u    // fp8[4224*512]
#define SQBW_OFF 4325376u    // float[4224]
#define SQBG_OFF 4342272u    // float[4224]
#define SCS_OFF  4359168u    // float[32][512] (zeroed)
#define SSP_OFF  4424704u    // double[256]    (zeroed)
#define PU_OFF   4426752u    // float[33][33][128] = 557568 (fully written)
#define PV_OFF   4984320u    // float[33][33][128]
#define PSL_OFF  5541888u    // double[561]    (fully written)
#define ZERO_BEG SCS_OFF
#define ZERO_END (SSP_OFF + 2048u)

__device__ __forceinline__ void atomAddF64(double* p, double v) {
  __hip_atomic_fetch_add(p, v, __ATOMIC_RELAXED, __HIP_MEMORY_SCOPE_AGENT);
}
__device__ __forceinline__ void atomAddF32(float* p, float v) {
  __hip_atomic_fetch_add(p, v, __ATOMIC_RELAXED, __HIP_MEMORY_SCOPE_AGENT);
}

// fast 2^x (range here: x <= 0, |x| modest; denormal flush is harmless)
__device__ __forceinline__ float fexp2(float x) {
  float r;
  asm("v_exp_f32 %0, %1" : "=v"(r) : "v"(x));
  return r;
}

// ---- fp8 e4m3fn decode (LUT build only) ----
__device__ __forceinline__ float fp8dec(unsigned b) {
  unsigned e = (b >> 3) & 15u, m = b & 7u;
  float v = ldexpf((float)(e ? (m | 8u) : m), (int)e - 10 + (e == 0));
  return (b & 0x80u) ? -v : v;
}

__device__ __forceinline__ unsigned f2fp8_manual(float f) {
  unsigned u = __float_as_uint(f);
  unsigned s = (u >> 24) & 0x80u;
  float a = __uint_as_float(u & 0x7FFFFFFFu);
  if (a >= 448.f) return s | 0x7Eu;
  if (a >= 0.015625f) {
    unsigned au = __float_as_uint(a);
    au += 0x7FFFFu + ((au >> 20) & 1u);
    unsigned e = (au >> 23) - 120u;
    unsigned m = (au >> 20) & 7u;
    if (e >= 16u) return s | 0x7Eu;
    return s | (e << 3) | m;
  }
  int q = (int)rintf(a * 512.f);
  return s | (unsigned)q;
}

#if __has_builtin(__builtin_amdgcn_cvt_pk_fp8_f32)
__device__ __forceinline__ unsigned pack4_fp8(float x0, float x1, float x2, float x3) {
  unsigned p = __builtin_amdgcn_cvt_pk_fp8_f32(x0, x1, 0, false);
  p = __builtin_amdgcn_cvt_pk_fp8_f32(x2, x3, p, true);
  return p;
}
#else
__device__ __forceinline__ unsigned pack4_fp8(float x0, float x1, float x2, float x3) {
  return f2fp8_manual(x0) | (f2fp8_manual(x1) << 8) |
         (f2fp8_manual(x2) << 16) | (f2fp8_manual(x3) << 24);
}
#endif

__device__ __forceinline__ void gload16(const void* g, void* l) {
  __builtin_amdgcn_global_load_lds(
      (const __attribute__((address_space(1))) unsigned int*)g,
      (__attribute__((address_space(3))) unsigned int*)l, 16, 0, 0);
}

// ---- prep: 16 rows/block; fp32->fp8; fp8-consistent row sumsq via LDS LUT; col sums
__global__ __launch_bounds__(256) void prep_rows(
    const float* __restrict__ W, const float* __restrict__ G,
    unsigned char* __restrict__ Wb, unsigned char* __restrict__ Gb,
    float* __restrict__ sqbW, float* __restrict__ sqbG,
    double* __restrict__ ssp, float* __restrict__ scs)
{
  __shared__ float colsLDS[4][512];
  __shared__ float lut2[256];          // dec(byte)^2
  const int bid = blockIdx.x;
  const int w = threadIdx.x >> 6;
  const int l = threadIdx.x & 63;

  if (bid >= 512) {                    // pad-row zeroing: 16 blocks x 16 rows
    #pragma unroll
    for (int it = 0; it < 4; ++it) {
      const int pr = (bid - 512) * 16 + it * 4 + w;   // 0..255
      const bool isG = pr >= 128;
      const int row = NROW + (pr & 127);
      unsigned char* dst = (isG ? Gb : Wb) + (size_t)row * DDIM;
      *(u32x2*)(dst + l * 8) = (u32x2){0u, 0u};
      if (l == 0) (isG ? sqbG : sqbW)[row] = 0.f;
    }
    return;
  }

  {
    const float d = fp8dec(threadIdx.x);
    lut2[threadIdx.x] = d * d;
  }
  __syncthreads();

  float colr[8] = {0.f,0.f,0.f,0.f,0.f,0.f,0.f,0.f};
  float s32 = 0.f;

  #pragma unroll
  for (int it = 0; it < 4; ++it) {
    const int row = bid * 16 + it * 4 + w;   // 0..8191
    const float* src; unsigned char* dst; float* sqb; int r;
    if (row < NROW) { src = W + (size_t)row * DDIM; dst = Wb + (size_t)row * DDIM; sqb = sqbW; r = row; }
    else            { src = G + (size_t)(row - NROW) * DDIM; dst = Gb + (size_t)(row - NROW) * DDIM; sqb = sqbG; r = row - NROW; }
    const f32x4 a = *(const f32x4*)(src + l * 8);
    const f32x4 b = *(const f32x4*)(src + l * 8 + 4);
    const unsigned p0 = pack4_fp8(a[0], a[1], a[2], a[3]);
    const unsigned p1 = pack4_fp8(b[0], b[1], b[2], b[3]);
    *(u32x2*)(dst + l * 8) = (u32x2){p0, p1};

    float sb = 0.f;
    #pragma unroll
    for (int j = 0; j < 4; ++j) {
      s32 += a[j] * a[j] + b[j] * b[j];
      colr[j] += a[j]; colr[4 + j] += b[j];
      sb += lut2[(p0 >> (8 * j)) & 0xFFu] + lut2[(p1 >> (8 * j)) & 0xFFu];
    }
    #pragma unroll
    for (int off = 32; off > 0; off >>= 1) sb += __shfl_down(sb, off);
    if (l == 0) sqb[r] = sb;
  }

  #pragma unroll
  for (int j = 0; j < 8; ++j) colsLDS[w][l * 8 + j] = colr[j];
  __syncthreads();
  {
    const int c = threadIdx.x;
    atomAddF32(&scs[(bid & 31) * 512 + c],
               colsLDS[0][c] + colsLDS[1][c] + colsLDS[2][c] + colsLDS[3][c]);
    const int c2 = c + 256;
    atomAddF32(&scs[(bid & 31) * 512 + c2],
               colsLDS[0][c2] + colsLDS[1][c2] + colsLDS[2][c2] + colsLDS[3][c2]);
  }
  #pragma unroll
  for (int off = 32; off > 0; off >>= 1) s32 += __shfl_down(s32, off);
  if (l == 0) atomAddF64(&ssp[bid & 255], (double)s32);
}

// ---- stage A (rows i0..) + B (rows j0..) panels of one matrix, K-half kh (256 B):
// 2 x 32 KiB. Linear LDS dest; 16B source slot pre-swizzled s ^ ((row>>1)&7).
__device__ __forceinline__ void stage_half(
    const unsigned char* __restrict__ mat, int i0, int j0, int kh,
    int tid, unsigned char* __restrict__ buf)
{
  #pragma unroll
  for (int q = 0; q < 8; ++q) {
    const int slot = q * 512 + tid;    // 0..4095
    const int panel = slot >> 11;      // 0=A, 1=B
    const int i = slot & 2047;
    const int row = i >> 4;            // 0..127
    const int s = i & 15;
    const int sp = s ^ ((row >> 1) & 7);
    const int rb = panel ? j0 : i0;
    gload16(mat + (size_t)(rb + row) * 512 + kh + sp * 16,
            buf + panel * 32768 + i * 16);
  }
}

// ---- compute one K=256 half into acc[2][4]; granule XOR j8^(row&14): conflict-free
__device__ __forceinline__ void compute_half(
    const unsigned char* __restrict__ buf,
    int wr, int wc, int lr, int g, f32x4 acc[2][4])
{
  #pragma unroll
  for (int kk = 0; kk < 8; ++kk) {
    long long a[2], b[4];
    const int j8 = kk * 4 + g;        // granule 0..31
    #pragma unroll
    for (int m = 0; m < 2; ++m) {
      const int row = wr * 32 + m * 16 + lr;
      a[m] = *(const long long*)(buf + row * 256 + ((j8 ^ (row & 14)) << 3));
    }
    #pragma unroll
    for (int n = 0; n < 4; ++n) {
      const int row = wc * 64 + n * 16 + lr;
      b[n] = *(const long long*)(buf + 32768 + row * 256 + ((j8 ^ (row & 14)) << 3));
    }
    __builtin_amdgcn_s_setprio(1);
    #pragma unroll
    for (int m = 0; m < 2; ++m)
      #pragma unroll
      for (int n = 0; n < 4; ++n)
        acc[m][n] = __builtin_amdgcn_mfma_f32_16x16x32_fp8_fp8(a[m], b[n], acc[m][n], 0, 0, 0);
    __builtin_amdgcn_s_setprio(0);
  }
}

// ---- main: 128^2 upper-tri tiles, 561 blocks, 8 waves (4x2), target 2 blocks/CU
__global__ __launch_bounds__(512, 4) void gram_kernel(
    const unsigned char* __restrict__ Wb, const unsigned char* __restrict__ Gb,
    const float* __restrict__ sqbW, const float* __restrict__ sqbG,
    const float* __restrict__ scs, const double* __restrict__ ssp,
    float* __restrict__ PU, float* __restrict__ PV, double* __restrict__ PSL)
{
  __shared__ __align__(16) unsigned char buf[65536];   // A|B panels, 32KB each
  __shared__ float L[512];   // rowW|rowG|colW|colG (128 each)
  __shared__ double pred[8], pred2[8];
  __shared__ float sS4;

  // T1: bijective XCD-chunked swizzle (nwg=561: q=70, r=1)
  const int orig = blockIdx.x;
  const int xcd = orig & 7;
  const int idx = orig >> 3;
  const int swz = (xcd == 0 ? 0 : 71 + (xcd - 1) * 70) + idx;

  // decode upper-triangular tile: 0 <= bi <= bj < 33
  int t = swz;
  int bi = 0;
  while (t >= NT - bi) { t -= NT - bi; ++bi; }
  const int bj = bi + t;
  const bool offdiag = (bi != bj);

  const int tid = threadIdx.x;
  const int lane = tid & 63;
  const int wid = tid >> 6;
  const int wr = wid >> 1;      // 0..3  (32-row band)
  const int wc = wid & 1;       // 0..1  (64-col half)
  const int i0 = bi * TS;
  const int j0 = bj * TS;
  const int g = lane >> 4;
  const int lr = lane & 15;

  f32x4 accW[2][4], accG[2][4];
  #pragma unroll
  for (int m = 0; m < 2; ++m)
    #pragma unroll
    for (int n = 0; n < 4; ++n) { accW[m][n] = (f32x4)0.0f; accG[m][n] = (f32x4)0.0f; }

  stage_half(Wb, i0, j0, 0, tid, buf);   __syncthreads();
  compute_half(buf, wr, wc, lr, g, accW); __syncthreads();
  stage_half(Wb, i0, j0, 256, tid, buf); __syncthreads();
  compute_half(buf, wr, wc, lr, g, accW); __syncthreads();
  stage_half(Gb, i0, j0, 0, tid, buf);   __syncthreads();
  compute_half(buf, wr, wc, lr, g, accG); __syncthreads();
  stage_half(Gb, i0, j0, 256, tid, buf); __syncthreads();
  compute_half(buf, wr, wc, lr, g, accG);

  // zero reduction arrays (512 threads, 512 slots, one pass)
  L[tid] = 0.f;

  // ---- folded bwk ----
  {
    float cs = 0.f;
    #pragma unroll 8
    for (int p = 0; p < 32; ++p) cs += scs[p * 512 + tid];
    double p1 = (double)cs * (double)cs;
    double p2 = (tid < 256) ? ssp[tid] : 0.0;
    #pragma unroll
    for (int off = 32; off > 0; off >>= 1) {
      p1 += __shfl_xor(p1, off);
      p2 += __shfl_xor(p2, off);
    }
    if (lane == 0) { pred[wid] = p1; pred2[wid] = p2; }
    __syncthreads();
    if (tid == 0) {
      double s2 = 0.0, ss = 0.0;
      #pragma unroll
      for (int k = 0; k < 8; ++k) { s2 += pred[k]; ss += pred2[k]; }
      double sum_d2 = 2.0 * 8192.0 * ss - 2.0 * s2;
      double bw = sum_d2 / (8192.0 * 8191.0) / 4.0;
      sS4 = (float)(1.4426950408889634 / (bw * 16.0));
    }
    __syncthreads();
  }
  const float s4 = sS4;

  // ---- epilogue: 32 evals per gram per thread, all f32 ----
  float rjW[4], rjG[4], mjf[4];
  #pragma unroll
  for (int n = 0; n < 4; ++n) {
    const int j = j0 + wc * 64 + n * 16 + lr;
    rjW[n] = sqbW[j]; rjG[n] = sqbG[j];
    mjf[n] = (j < NROW) ? 1.f : 0.f;
  }

  float csW[4] = {0.f,0.f,0.f,0.f}, csG[4] = {0.f,0.f,0.f,0.f};
  float rsW[2][4], rsG[2][4];
  float p_loc = 0.f;

  #pragma unroll
  for (int m = 0; m < 2; ++m) {
    const int ib = i0 + wr * 32 + m * 16 + g * 4;
    float riW[4], riG[4], mif[4];
    #pragma unroll
    for (int e = 0; e < 4; ++e) {
      riW[e] = sqbW[ib + e]; riG[e] = sqbG[ib + e];
      mif[e] = (ib + e < NROW) ? 1.f : 0.f;
    }
    #pragma unroll
    for (int e = 0; e < 4; ++e) { rsW[m][e] = 0.f; rsG[m][e] = 0.f; }
    #pragma unroll
    for (int n = 0; n < 4; ++n) {
      #pragma unroll
      for (int e = 0; e < 4; ++e) {
        const float mk = mif[e] * mjf[n];
        float d2w = fmaxf(riW[e] + rjW[n] - 2.f * accW[m][n][e], 0.f);
        float yw = fexp2(-d2w * s4);
        float yw2 = yw * yw, yw4 = yw2 * yw2, yw8 = yw4 * yw4, yw16 = yw8 * yw8;
        float kw = (yw + yw2 + yw4 + yw8 + yw16) * mk;
        float d2g = fmaxf(riG[e] + rjG[n] - 2.f * accG[m][n][e], 0.f);
        float yg = fexp2(-d2g * s4);
        float yg2 = yg * yg, yg4 = yg2 * yg2, yg8 = yg4 * yg4, yg16 = yg8 * yg8;
        float kg = (yg + yg2 + yg4 + yg8 + yg16) * mk;
        p_loc = fmaf(kw, kg, p_loc);
        rsW[m][e] += kw; rsG[m][e] += kg;
        csW[n] += kw; csG[n] += kg;
      }
    }
  }

  __syncthreads();   // L zeroing + buf-dead visible

  // row sums -> LDS (butterfly over 16 column-lanes; 2 wc-waves share a slot)
  #pragma unroll
  for (int m = 0; m < 2; ++m)
    #pragma unroll
    for (int e = 0; e < 4; ++e) {
      float x = rsW[m][e], y = rsG[m][e];
      x += __shfl_xor(x, 1); x += __shfl_xor(x, 2); x += __shfl_xor(x, 4); x += __shfl_xor(x, 8);
      y += __shfl_xor(y, 1); y += __shfl_xor(y, 2); y += __shfl_xor(y, 4); y += __shfl_xor(y, 8);
      if (lr == 0) {
        const int rloc = wr * 32 + m * 16 + g * 4 + e;   // 0..127
        atomicAdd(&L[rloc], x);
        atomicAdd(&L[128 + rloc], y);
      }
    }

  // col sums -> LDS (butterfly over g-groups; 4 wr-waves share a slot)
  if (offdiag) {
    #pragma unroll
    for (int n = 0; n < 4; ++n) {
      float x = csW[n], y = csG[n];
      x += __shfl_xor(x, 16); x += __shfl_xor(x, 32);
      y += __shfl_xor(y, 16); y += __shfl_xor(y, 32);
      if (g == 0) {
        const int cloc = wc * 64 + n * 16 + lr;          // 0..127
        atomicAdd(&L[256 + cloc], x);
        atomicAdd(&L[384 + cloc], y);
      }
    }
  }

  __syncthreads();

  // plain coalesced partial stores (no global atomics)
  if (tid < 128) {
    PU[(bi * NT + bj) * 128 + tid] = L[tid];
    PV[(bi * NT + bj) * 128 + tid] = L[128 + tid];
    if (offdiag) {
      PU[(bj * NT + bi) * 128 + tid] = L[256 + tid];
      PV[(bj * NT + bi) * 128 + tid] = L[384 + tid];
    }
  }

  // P: f32 wave butterfly -> f64 block sum -> one plain store per tile
  #pragma unroll
  for (int off = 32; off > 0; off >>= 1) p_loc += __shfl_xor(p_loc, off);
  if (lane == 0) pred[wid] = (double)p_loc;
  __syncthreads();
  if (tid == 0) {
    double ps = 0.0;
    #pragma unroll
    for (int k = 0; k < 8; ++k) ps += pred[k];
    PSL[swz] = offdiag ? 2.0 * ps : ps;
  }
}

// ---- finalize: u,v from partials; loss
__global__ __launch_bounds__(1024) void finalize(
    const float* __restrict__ PU, const float* __restrict__ PV,
    const double* __restrict__ PSL, float* __restrict__ out)
{
  __shared__ double r0[1024], r1[1024], r2[1024], r3[1024];
  const int t = threadIdx.x;
  double uv = 0.0, su = 0.0, sv = 0.0, pp = 0.0;
  for (int i = t; i < NPAD; i += 1024) {
    const int b = i >> 7, ii = i & 127;
    double uu = 0.0, vv = 0.0;
    #pragma unroll
    for (int k = 0; k < NT; ++k) {
      uu += (double)PU[(b * NT + k) * 128 + ii];
      vv += (double)PV[(b * NT + k) * 128 + ii];
    }
    uv += uu * vv; su += uu; sv += vv;
  }
  if (t < 561) pp = PSL[t];
  r0[t] = uv; r1[t] = su; r2[t] = sv; r3[t] = pp;
  __syncthreads();
  for (int k = 512; k > 0; k >>= 1) {
    if (t < k) { r0[t] += r0[t + k]; r1[t] += r1[t + k]; r2[t] += r2[t + k]; r3[t] += r3[t + k]; }
    __syncthreads();
  }
  if (t == 0) {
    const double n = 4096.0;
    double hsic = r3[0] - (2.0 / n) * r0[0] + (r1[0] * r2[0]) / (n * n);
    out[0] = (float)(-hsic / ((n - 1.0) * (n - 1.0)));
  }
}

extern "C" void kernel_launch(void* const* d_in, const int* in_sizes, int n_in,
                              void* d_out, int out_size, void* d_ws, size_t ws_size,
                              hipStream_t stream) {
  const float* W = (const float*)d_in[0];
  const float* G = (const float*)d_in[1];
  char* ws = (char*)d_ws;
  unsigned char* Wb = (unsigned char*)(ws + WB_OFF);
  unsigned char* Gb = (unsigned char*)(ws + GB_OFF);
  float* sqbW = (float*)(ws + SQBW_OFF);
  float* sqbG = (float*)(ws + SQBG_OFF);
  float* scs = (float*)(ws + SCS_OFF);
  double* ssp = (double*)(ws + SSP_OFF);
  float* PU = (float*)(ws + PU_OFF);
  float* PV = (float*)(ws + PV_OFF);
  double* PSL = (double*)(ws + PSL_OFF);

  hipMemsetAsync(ws + ZERO_BEG, 0, ZERO_END - ZERO_BEG, stream);

  prep_rows<<<528, 256, 0, stream>>>(W, G, Wb, Gb, sqbW, sqbG, ssp, scs);
  gram_kernel<<<561, 512, 0, stream>>>(Wb, Gb, sqbW, sqbG, scs, ssp, PU, PV, PSL);
  finalize<<<1, 1024, 0, stream>>>(PU, PV, PSL, (float*)d_out);
}

// Round 12
// 64.787 us; speedup vs baseline: 1.2322x; 1.1169x over previous
//
#include <hip/hip_runtime.h>
#include <stdint.h>

typedef __attribute__((ext_vector_type(4))) float f32x4;
typedef __attribute__((ext_vector_type(2))) unsigned int u32x2;

#define NROW 4096
#define DDIM 512
#define NT   22            // tiles per dim
#define TS   192
#define NPAD 4224

// ---------------- ws layout (bytes) ----------------
#define WB_OFF   0u          // fp8[4224*512] = 2162688
#define GB_OFF   2162688u    // fp8[4224*512]
#define SQBW_OFF 4325376u    // float[4224]
#define SQBG_OFF 4342272u    // float[4224]
#define SCS_OFF  4359168u    // float[32][512] (zeroed)
#define SSP_OFF  4424704u    // double[256]    (zeroed)
#define PU_OFF   4426752u    // float[22][22][192] = 371712 (fully written)
#define PV_OFF   4798464u    // float[22][22][192]
#define PSL_OFF  5170176u    // double[253]    (fully written)
#define ZERO_BEG SCS_OFF
#define ZERO_END (SSP_OFF + 2048u)

__device__ __forceinline__ void atomAddF64(double* p, double v) {
  __hip_atomic_fetch_add(p, v, __ATOMIC_RELAXED, __HIP_MEMORY_SCOPE_AGENT);
}
__device__ __forceinline__ void atomAddF32(float* p, float v) {
  __hip_atomic_fetch_add(p, v, __ATOMIC_RELAXED, __HIP_MEMORY_SCOPE_AGENT);
}

// fast 2^x (x <= 0, modest |x|; denormal flush harmless) — validated R11
__device__ __forceinline__ float fexp2(float x) {
  float r;
  asm("v_exp_f32 %0, %1" : "=v"(r) : "v"(x));
  return r;
}

// ---- fp8 e4m3fn helpers ----
__device__ __forceinline__ float fp8dec(unsigned b) {
  unsigned e = (b >> 3) & 15u, m = b & 7u;
  float v = ldexpf((float)(e ? (m | 8u) : m), (int)e - 10 + (e == 0));
  return (b & 0x80u) ? -v : v;
}

__device__ __forceinline__ unsigned f2fp8_manual(float f) {
  unsigned u = __float_as_uint(f);
  unsigned s = (u >> 24) & 0x80u;
  float a = __uint_as_float(u & 0x7FFFFFFFu);
  if (a >= 448.f) return s | 0x7Eu;
  if (a >= 0.015625f) {
    unsigned au = __float_as_uint(a);
    au += 0x7FFFFu + ((au >> 20) & 1u);
    unsigned e = (au >> 23) - 120u;
    unsigned m = (au >> 20) & 7u;
    if (e >= 16u) return s | 0x7Eu;
    return s | (e << 3) | m;
  }
  int q = (int)rintf(a * 512.f);
  return s | (unsigned)q;
}

#if __has_builtin(__builtin_amdgcn_cvt_pk_fp8_f32)
__device__ __forceinline__ unsigned pack4_fp8(float x0, float x1, float x2, float x3) {
  unsigned p = __builtin_amdgcn_cvt_pk_fp8_f32(x0, x1, 0, false);
  p = __builtin_amdgcn_cvt_pk_fp8_f32(x2, x3, p, true);
  return p;
}
#else
__device__ __forceinline__ unsigned pack4_fp8(float x0, float x1, float x2, float x3) {
  return f2fp8_manual(x0) | (f2fp8_manual(x1) << 8) |
         (f2fp8_manual(x2) << 16) | (f2fp8_manual(x3) << 24);
}
#endif

__device__ __forceinline__ void gload16(const void* g, void* l) {
  __builtin_amdgcn_global_load_lds(
      (const __attribute__((address_space(1))) unsigned int*)g,
      (__attribute__((address_space(3))) unsigned int*)l, 16, 0, 0);
}

// ---- prep (R8 verbatim): fp32->fp8, fp8-consistent row sumsq, fused column sums
__global__ __launch_bounds__(256) void prep_rows(
    const float* __restrict__ W, const float* __restrict__ G,
    unsigned char* __restrict__ Wb, unsigned char* __restrict__ Gb,
    float* __restrict__ sqbW, float* __restrict__ sqbG,
    double* __restrict__ ssp, float* __restrict__ scs)
{
  __shared__ float cols[4][512];
  const int bid = blockIdx.x;
  const int w = threadIdx.x >> 6;
  const int l = threadIdx.x & 63;

  if (bid >= 2048) {                       // pad-row zeroing blocks
    const int pr = (bid - 2048) * 4 + w;   // 0..255
    const bool isG = pr >= 128;
    const int row = NROW + (pr & 127);     // 4096..4223
    unsigned char* dst = (isG ? Gb : Wb) + (size_t)row * DDIM;
    *(u32x2*)(dst + l * 8) = (u32x2){0u, 0u};
    if (l == 0) (isG ? sqbG : sqbW)[row] = 0.f;
    return;
  }

  const int row = bid * 4 + w;             // 0..8191
  const float* src; unsigned char* dst; float* sqb; int r;
  if (row < NROW) { src = W + (size_t)row * DDIM; dst = Wb + (size_t)row * DDIM; sqb = sqbW; r = row; }
  else            { src = G + (size_t)(row - NROW) * DDIM; dst = Gb + (size_t)(row - NROW) * DDIM; sqb = sqbG; r = row - NROW; }
  const f32x4 a = *(const f32x4*)(src + l * 8);
  const f32x4 b = *(const f32x4*)(src + l * 8 + 4);

  const unsigned p0 = pack4_fp8(a[0], a[1], a[2], a[3]);
  const unsigned p1 = pack4_fp8(b[0], b[1], b[2], b[3]);
  *(u32x2*)(dst + l * 8) = (u32x2){p0, p1};

  float s32 = 0.f, sb = 0.f;
  #pragma unroll
  for (int j = 0; j < 4; ++j) { s32 += a[j] * a[j]; s32 += b[j] * b[j]; }
  #pragma unroll
  for (int j = 0; j < 4; ++j) {
    float xa = fp8dec((p0 >> (8 * j)) & 0xFFu);
    float xb = fp8dec((p1 >> (8 * j)) & 0xFFu);
    sb += xa * xa + xb * xb;
  }

  *(f32x4*)&cols[w][l * 8] = a;
  *(f32x4*)&cols[w][l * 8 + 4] = b;
  __syncthreads();
  for (int c = threadIdx.x; c < 512; c += 256)
    atomAddF32(&scs[(bid & 31) * 512 + c],
               cols[0][c] + cols[1][c] + cols[2][c] + cols[3][c]);

  #pragma unroll
  for (int off = 32; off > 0; off >>= 1) { s32 += __shfl_down(s32, off); sb += __shfl_down(sb, off); }
  if (l == 0) { sqb[r] = sb; atomAddF64(&ssp[bid & 255], (double)s32); }
}

// ---- stage one BK=64 K-step: 4 fp8 panels AW|BW|AG|BG (192x64 B = 12288 B each)
// (R6 verbatim; linear LDS dest; 16B source slot pre-swizzled c = s ^ ((row>>1)&3))
__device__ __forceinline__ void stage_step(
    const unsigned char* __restrict__ Wb, const unsigned char* __restrict__ Gb,
    int i0, int j0, int st, int tid, unsigned char* __restrict__ buf)
{
  const int kb = st * 64;
  #pragma unroll
  for (int q = 0; q < 6; ++q) {
    const int slot = q * 512 + tid;   // 0..3071, 16B each; panels of 768 slots
    int p;
    if (q == 0) p = 0;
    else if (q == 1) p = (slot < 768) ? 0 : 1;
    else if (q == 2) p = 1;
    else if (q == 3) p = 2;
    else if (q == 4) p = (slot < 2304) ? 2 : 3;
    else p = 3;
    const unsigned char* mat = (p < 2) ? Wb : Gb;
    const int rb = (p & 1) ? j0 : i0;
    const int r = slot - p * 768;
    const int row = r >> 2;
    const int c = (r & 3) ^ ((row >> 1) & 3);
    gload16(mat + (size_t)(rb + row) * 512 + kb + c * 16, buf + slot * 16);
  }
}

// ---- one K=64 step (2 x K=32 MFMA) for one gram (R6 verbatim)
__device__ __forceinline__ void gram_pass(
    const unsigned char* __restrict__ A, const unsigned char* __restrict__ B,
    int wr, int wc, int lr, int g, f32x4 acc[6][3])
{
  #pragma unroll
  for (int kk = 0; kk < 2; ++kk) {
    long long a[6], b[3];
    #pragma unroll
    for (int m = 0; m < 6; ++m) {
      const int row = wr * 96 + m * 16 + lr;
      const int off = row * 64 + (((kk * 2 + (g >> 1)) ^ ((row >> 1) & 3)) << 4) + ((g & 1) << 3);
      a[m] = *(const long long*)(A + off);
    }
    #pragma unroll
    for (int n = 0; n < 3; ++n) {
      const int row = wc * 48 + n * 16 + lr;
      const int off = row * 64 + (((kk * 2 + (g >> 1)) ^ ((row >> 1) & 3)) << 4) + ((g & 1) << 3);
      b[n] = *(const long long*)(B + off);
    }
    __builtin_amdgcn_s_setprio(1);
    #pragma unroll
    for (int m = 0; m < 6; ++m)
      #pragma unroll
      for (int n = 0; n < 3; ++n)
        acc[m][n] = __builtin_amdgcn_mfma_f32_16x16x32_fp8_fp8(a[m], b[n], acc[m][n], 0, 0, 0);
    __builtin_amdgcn_s_setprio(0);
  }
}

// ---- main: 192^2 upper-tri tiles, T3-minimum issue-early double-buffer pipeline
__global__ __launch_bounds__(512, 1) void gram_kernel(
    const unsigned char* __restrict__ Wb, const unsigned char* __restrict__ Gb,
    const float* __restrict__ sqbW, const float* __restrict__ sqbG,
    const float* __restrict__ scs, const double* __restrict__ ssp,
    float* __restrict__ PU, float* __restrict__ PV, double* __restrict__ PSL)
{
  __shared__ __align__(16) unsigned char lds[2][49152];  // dbuf: AW|BW|AG|BG each
  __shared__ float L[768];   // rowW|rowG|colW|colG reduction arrays
  __shared__ double pred[8], pred2[8];
  __shared__ float sS4;

  // T1: bijective XCD-chunked swizzle (nwg=253: q=31, r=5)
  const int orig = blockIdx.x;
  const int xcd = orig & 7;
  const int idx = orig >> 3;
  const int swz = (xcd < 5 ? xcd * 32 : 5 * 32 + (xcd - 5) * 31) + idx;

  // decode upper-triangular tile index: 0 <= bi <= bj < 22
  int t = swz;
  int bi = 0;
  while (t >= NT - bi) { t -= NT - bi; ++bi; }
  const int bj = bi + t;
  const bool offdiag = (bi != bj);

  const int tid = threadIdx.x;
  const int lane = tid & 63;
  const int wid = tid >> 6;
  const int wr = wid >> 2;      // 0..1  (96-row half)
  const int wc = wid & 3;       // 0..3  (48-col quarter)
  const int i0 = bi * TS;
  const int j0 = bj * TS;
  const int g = lane >> 4;
  const int lr = lane & 15;

  f32x4 accW[6][3], accG[6][3];
  #pragma unroll
  for (int m = 0; m < 6; ++m)
    #pragma unroll
    for (int n = 0; n < 3; ++n) { accW[m][n] = (f32x4)0.0f; accG[m][n] = (f32x4)0.0f; }

  // prologue: stage K-step 0, full drain
  stage_step(Wb, Gb, i0, j0, 0, tid, lds[0]);
  __syncthreads();

  // T3-minimum: issue next-step loads BEFORE compute; one drain+barrier per step.
  // The stage(st+1) flight hides under 72 MFMAs + 36 b64 reads of step st.
  for (int st = 0; st < 8; ++st) {
    unsigned char* cur = lds[st & 1];
    if (st < 7)
      stage_step(Wb, Gb, i0, j0, st + 1, tid, lds[(st + 1) & 1]);
    __builtin_amdgcn_sched_barrier(0);   // pin: loads issue before compute
    gram_pass(cur, cur + 12288, wr, wc, lr, g, accW);
    gram_pass(cur + 24576, cur + 36864, wr, wc, lr, g, accG);
    __syncthreads();   // drains residual flight; protects buf swap
  }

  // ---- folded bwk: bandwidth scale computed redundantly per block ----
  {
    float cs = 0.f;
    #pragma unroll 8
    for (int p = 0; p < 32; ++p) cs += scs[p * 512 + tid];
    double p1 = (double)cs * (double)cs;
    double p2 = (tid < 256) ? ssp[tid] : 0.0;
    #pragma unroll
    for (int off = 32; off > 0; off >>= 1) {
      p1 += __shfl_xor(p1, off);
      p2 += __shfl_xor(p2, off);
    }
    if (lane == 0) { pred[wid] = p1; pred2[wid] = p2; }
    __syncthreads();
    if (tid == 0) {
      double s2 = 0.0, ss = 0.0;
      #pragma unroll
      for (int k = 0; k < 8; ++k) { s2 += pred[k]; ss += pred2[k]; }
      double sum_d2 = 2.0 * 8192.0 * ss - 2.0 * s2;
      double bw = sum_d2 / (8192.0 * 8191.0) / 4.0;
      sS4 = (float)(1.4426950408889634 / (bw * 16.0));
    }
    __syncthreads();
  }
  const float s4 = sS4;

  // zero ALL 768 reduction slots (512 threads: two passes)
  L[tid] = 0.f;
  if (tid < 256) L[512 + tid] = 0.f;

  // ---- epilogue: kernel values (f32, fexp2 — validated R11) ----
  float rjW[3], rjG[3], mjf[3];
  #pragma unroll
  for (int n = 0; n < 3; ++n) {
    const int j = j0 + wc * 48 + n * 16 + lr;
    rjW[n] = sqbW[j]; rjG[n] = sqbG[j];
    mjf[n] = (j < NROW) ? 1.f : 0.f;
  }

  float csW[3] = {0.f, 0.f, 0.f}, csG[3] = {0.f, 0.f, 0.f};
  float rsW[6][4], rsG[6][4];
  float p_loc = 0.f;

  #pragma unroll
  for (int m = 0; m < 6; ++m) {
    const int ib = i0 + wr * 96 + m * 16 + g * 4;
    float riW[4], riG[4], mif[4];
    #pragma unroll
    for (int e = 0; e < 4; ++e) {
      riW[e] = sqbW[ib + e]; riG[e] = sqbG[ib + e];
      mif[e] = (ib + e < NROW) ? 1.f : 0.f;
    }
    #pragma unroll
    for (int e = 0; e < 4; ++e) { rsW[m][e] = 0.f; rsG[m][e] = 0.f; }
    #pragma unroll
    for (int n = 0; n < 3; ++n) {
      #pragma unroll
      for (int e = 0; e < 4; ++e) {
        const float mk = mif[e] * mjf[n];
        float d2w = fmaxf(riW[e] + rjW[n] - 2.f * accW[m][n][e], 0.f);
        float yw = fexp2(-d2w * s4);
        float yw2 = yw * yw, yw4 = yw2 * yw2, yw8 = yw4 * yw4, yw16 = yw8 * yw8;
        float kw = (yw + yw2 + yw4 + yw8 + yw16) * mk;
        float d2g = fmaxf(riG[e] + rjG[n] - 2.f * accG[m][n][e], 0.f);
        float yg = fexp2(-d2g * s4);
        float yg2 = yg * yg, yg4 = yg2 * yg2, yg8 = yg4 * yg4, yg16 = yg8 * yg8;
        float kg = (yg + yg2 + yg4 + yg8 + yg16) * mk;
        p_loc = fmaf(kw, kg, p_loc);
        rsW[m][e] += kw; rsG[m][e] += kg;
        csW[n] += kw; csG[n] += kg;
      }
    }
  }

  __syncthreads();   // L zeroing visible

  // row sums -> LDS (butterfly over the 16 column-lanes, then 4-way LDS atomic)
  #pragma unroll
  for (int m = 0; m < 6; ++m)
    #pragma unroll
    for (int e = 0; e < 4; ++e) {
      float x = rsW[m][e], y = rsG[m][e];
      x += __shfl_xor(x, 1); x += __shfl_xor(x, 2); x += __shfl_xor(x, 4); x += __shfl_xor(x, 8);
      y += __shfl_xor(y, 1); y += __shfl_xor(y, 2); y += __shfl_xor(y, 4); y += __shfl_xor(y, 8);
      if (lr == 0) {
        const int rloc = wr * 96 + m * 16 + g * 4 + e;   // 0..191
        atomicAdd(&L[rloc], x);
        atomicAdd(&L[192 + rloc], y);
      }
    }

  // col sums -> LDS (butterfly over g-groups, then 2-way LDS atomic)
  if (offdiag) {
    #pragma unroll
    for (int n = 0; n < 3; ++n) {
      float x = csW[n], y = csG[n];
      x += __shfl_xor(x, 16); x += __shfl_xor(x, 32);
      y += __shfl_xor(y, 16); y += __shfl_xor(y, 32);
      if (g == 0) {
        const int cloc = wc * 48 + n * 16 + lr;          // 0..191
        atomicAdd(&L[384 + cloc], x);
        atomicAdd(&L[576 + cloc], y);
      }
    }
  }

  __syncthreads();

  // plain coalesced partial stores (no global atomics)
  if (tid < 192) {
    PU[(bi * NT + bj) * 192 + tid] = L[tid];
    PV[(bi * NT + bj) * 192 + tid] = L[192 + tid];
    if (offdiag) {
      PU[(bj * NT + bi) * 192 + tid] = L[384 + tid];
      PV[(bj * NT + bi) * 192 + tid] = L[576 + tid];
    }
  }

  // P: f32 wave butterfly -> f64 block sum -> one plain store per tile
  #pragma unroll
  for (int off = 32; off > 0; off >>= 1) p_loc += __shfl_xor(p_loc, off);
  if (lane == 0) pred[wid] = (double)p_loc;
  __syncthreads();
  if (tid == 0) {
    double ps = 0.0;
    #pragma unroll
    for (int k = 0; k < 8; ++k) ps += pred[k];
    PSL[swz] = offdiag ? 2.0 * ps : ps;
  }
}

// ---- finalize (single launch): u,v from partials; loss
__global__ __launch_bounds__(1024) void finalize(
    const float* __restrict__ PU, const float* __restrict__ PV,
    const double* __restrict__ PSL, float* __restrict__ out)
{
  __shared__ double r0[1024], r1[1024], r2[1024], r3[1024];
  const int t = threadIdx.x;
  double uv = 0.0, su = 0.0, sv = 0.0, pp = 0.0;
  for (int i = t; i < NPAD; i += 1024) {
    const int b = i / 192, ii = i - b * 192;
    double uu = 0.0, vv = 0.0;
    #pragma unroll
    for (int k = 0; k < NT; ++k) {
      uu += (double)PU[(b * NT + k) * 192 + ii];
      vv += (double)PV[(b * NT + k) * 192 + ii];
    }
    uv += uu * vv; su += uu; sv += vv;
  }
  if (t < 253) pp = PSL[t];
  r0[t] = uv; r1[t] = su; r2[t] = sv; r3[t] = pp;
  __syncthreads();
  for (int k = 512; k > 0; k >>= 1) {
    if (t < k) { r0[t] += r0[t + k]; r1[t] += r1[t + k]; r2[t] += r2[t + k]; r3[t] += r3[t + k]; }
    __syncthreads();
  }
  if (t == 0) {
    const double n = 4096.0;
    double hsic = r3[0] - (2.0 / n) * r0[0] + (r1[0] * r2[0]) / (n * n);
    out[0] = (float)(-hsic / ((n - 1.0) * (n - 1.0)));
  }
}

extern "C" void kernel_launch(void* const* d_in, const int* in_sizes, int n_in,
                              void* d_out, int out_size, void* d_ws, size_t ws_size,
                              hipStream_t stream) {
  const float* W = (const float*)d_in[0];
  const float* G = (const float*)d_in[1];
  char* ws = (char*)d_ws;
  unsigned char* Wb = (unsigned char*)(ws + WB_OFF);
  unsigned char* Gb = (unsigned char*)(ws + GB_OFF);
  float* sqbW = (float*)(ws + SQBW_OFF);
  float* sqbG = (float*)(ws + SQBG_OFF);
  float* scs = (float*)(ws + SCS_OFF);
  double* ssp = (double*)(ws + SSP_OFF);
  float* PU = (float*)(ws + PU_OFF);
  float* PV = (float*)(ws + PV_OFF);
  double* PSL = (double*)(ws + PSL_OFF);

  hipMemsetAsync(ws + ZERO_BEG, 0, ZERO_END - ZERO_BEG, stream);

  prep_rows<<<2112, 256, 0, stream>>>(W, G, Wb, Gb, sqbW, sqbG, ssp, scs);
  gram_kernel<<<253, 512, 0, stream>>>(Wb, Gb, sqbW, sqbG, scs, ssp, PU, PV, PSL);
  finalize<<<1, 1024, 0, stream>>>(PU, PV, PSL, (float*)d_out);
}

// Round 13
// 62.614 us; speedup vs baseline: 1.2749x; 1.0347x over previous
//
#include <hip/hip_runtime.h>
#include <stdint.h>

typedef __attribute__((ext_vector_type(4))) float f32x4;
typedef __attribute__((ext_vector_type(2))) unsigned int u32x2;
typedef __attribute__((ext_vector_type(4))) unsigned int u32x4;

#define NROW 4096
#define DDIM 512
#define NT   22            // tiles per dim
#define TS   192
#define NPAD 4224

// ---------------- ws layout (bytes) ----------------
#define WB_OFF   0u          // fp8[4224*512] = 2162688
#define GB_OFF   2162688u    // fp8[4224*512]
#define SQBW_OFF 4325376u    // float[4224]
#define SQBG_OFF 4342272u    // float[4224]
#define SCS_OFF  4359168u    // float[32][512] (zeroed)
#define SSP_OFF  4424704u    // double[256]    (zeroed)
#define PU_OFF   4426752u    // float[22][22][192] = 371712 (fully written)
#define PV_OFF   4798464u    // float[22][22][192]
#define PSL_OFF  5170176u    // double[253]    (fully written)
#define ZERO_BEG SCS_OFF
#define ZERO_END (SSP_OFF + 2048u)

// raw barrier: drains LDS ops only — in-flight global loads stay in flight (T4)
#define BAR_LGKM() asm volatile("s_waitcnt lgkmcnt(0)\n\ts_barrier" ::: "memory")

__device__ __forceinline__ void atomAddF64(double* p, double v) {
  __hip_atomic_fetch_add(p, v, __ATOMIC_RELAXED, __HIP_MEMORY_SCOPE_AGENT);
}
__device__ __forceinline__ void atomAddF32(float* p, float v) {
  __hip_atomic_fetch_add(p, v, __ATOMIC_RELAXED, __HIP_MEMORY_SCOPE_AGENT);
}

// fast 2^x (x <= 0, modest |x|; denormal flush harmless) — validated R11
__device__ __forceinline__ float fexp2(float x) {
  float r;
  asm("v_exp_f32 %0, %1" : "=v"(r) : "v"(x));
  return r;
}

// ---- fp8 e4m3fn helpers ----
__device__ __forceinline__ float fp8dec(unsigned b) {
  unsigned e = (b >> 3) & 15u, m = b & 7u;
  float v = ldexpf((float)(e ? (m | 8u) : m), (int)e - 10 + (e == 0));
  return (b & 0x80u) ? -v : v;
}

__device__ __forceinline__ unsigned f2fp8_manual(float f) {
  unsigned u = __float_as_uint(f);
  unsigned s = (u >> 24) & 0x80u;
  float a = __uint_as_float(u & 0x7FFFFFFFu);
  if (a >= 448.f) return s | 0x7Eu;
  if (a >= 0.015625f) {
    unsigned au = __float_as_uint(a);
    au += 0x7FFFFu + ((au >> 20) & 1u);
    unsigned e = (au >> 23) - 120u;
    unsigned m = (au >> 20) & 7u;
    if (e >= 16u) return s | 0x7Eu;
    return s | (e << 3) | m;
  }
  int q = (int)rintf(a * 512.f);
  return s | (unsigned)q;
}

#if __has_builtin(__builtin_amdgcn_cvt_pk_fp8_f32)
__device__ __forceinline__ unsigned pack4_fp8(float x0, float x1, float x2, float x3) {
  unsigned p = __builtin_amdgcn_cvt_pk_fp8_f32(x0, x1, 0, false);
  p = __builtin_amdgcn_cvt_pk_fp8_f32(x2, x3, p, true);
  return p;
}
#else
__device__ __forceinline__ unsigned pack4_fp8(float x0, float x1, float x2, float x3) {
  return f2fp8_manual(x0) | (f2fp8_manual(x1) << 8) |
         (f2fp8_manual(x2) << 16) | (f2fp8_manual(x3) << 24);
}
#endif

// ---- prep (R8 verbatim): fp32->fp8, fp8-consistent row sumsq, fused column sums
__global__ __launch_bounds__(256) void prep_rows(
    const float* __restrict__ W, const float* __restrict__ G,
    unsigned char* __restrict__ Wb, unsigned char* __restrict__ Gb,
    float* __restrict__ sqbW, float* __restrict__ sqbG,
    double* __restrict__ ssp, float* __restrict__ scs)
{
  __shared__ float cols[4][512];
  const int bid = blockIdx.x;
  const int w = threadIdx.x >> 6;
  const int l = threadIdx.x & 63;

  if (bid >= 2048) {                       // pad-row zeroing blocks
    const int pr = (bid - 2048) * 4 + w;   // 0..255
    const bool isG = pr >= 128;
    const int row = NROW + (pr & 127);     // 4096..4223
    unsigned char* dst = (isG ? Gb : Wb) + (size_t)row * DDIM;
    *(u32x2*)(dst + l * 8) = (u32x2){0u, 0u};
    if (l == 0) (isG ? sqbG : sqbW)[row] = 0.f;
    return;
  }

  const int row = bid * 4 + w;             // 0..8191
  const float* src; unsigned char* dst; float* sqb; int r;
  if (row < NROW) { src = W + (size_t)row * DDIM; dst = Wb + (size_t)row * DDIM; sqb = sqbW; r = row; }
  else            { src = G + (size_t)(row - NROW) * DDIM; dst = Gb + (size_t)(row - NROW) * DDIM; sqb = sqbG; r = row - NROW; }
  const f32x4 a = *(const f32x4*)(src + l * 8);
  const f32x4 b = *(const f32x4*)(src + l * 8 + 4);

  const unsigned p0 = pack4_fp8(a[0], a[1], a[2], a[3]);
  const unsigned p1 = pack4_fp8(b[0], b[1], b[2], b[3]);
  *(u32x2*)(dst + l * 8) = (u32x2){p0, p1};

  float s32 = 0.f, sb = 0.f;
  #pragma unroll
  for (int j = 0; j < 4; ++j) { s32 += a[j] * a[j]; s32 += b[j] * b[j]; }
  #pragma unroll
  for (int j = 0; j < 4; ++j) {
    float xa = fp8dec((p0 >> (8 * j)) & 0xFFu);
    float xb = fp8dec((p1 >> (8 * j)) & 0xFFu);
    sb += xa * xa + xb * xb;
  }

  *(f32x4*)&cols[w][l * 8] = a;
  *(f32x4*)&cols[w][l * 8 + 4] = b;
  __syncthreads();
  for (int c = threadIdx.x; c < 512; c += 256)
    atomAddF32(&scs[(bid & 31) * 512 + c],
               cols[0][c] + cols[1][c] + cols[2][c] + cols[3][c]);

  #pragma unroll
  for (int off = 32; off > 0; off >>= 1) { s32 += __shfl_down(s32, off); sb += __shfl_down(sb, off); }
  if (l == 0) { sqb[r] = sb; atomAddF64(&ssp[bid & 255], (double)s32); }
}

// ---- issue 6 global_load_dwordx4 for one BK=64 step into regs (T14 issue-early).
// Same slot->address mapping as R6's stage_step (swizzled source, linear LDS dest).
__device__ __forceinline__ void issue_loads(
    const unsigned char* __restrict__ Wb, const unsigned char* __restrict__ Gb,
    int i0, int j0, int st, int tid, u32x4 r[6])
{
  const int kb = st * 64;
  #pragma unroll
  for (int q = 0; q < 6; ++q) {
    const int slot = q * 512 + tid;   // 0..3071, 16B each; panels of 768 slots
    int p;
    if (q == 0) p = 0;
    else if (q == 1) p = (slot < 768) ? 0 : 1;
    else if (q == 2) p = 1;
    else if (q == 3) p = 2;
    else if (q == 4) p = (slot < 2304) ? 2 : 3;
    else p = 3;
    const unsigned char* mat = (p < 2) ? Wb : Gb;
    const int rb = (p & 1) ? j0 : i0;
    const int rr = slot - p * 768;
    const int row = rr >> 2;
    const int c = (rr & 3) ^ ((row >> 1) & 3);
    r[q] = *(const u32x4*)(mat + (size_t)(rb + row) * 512 + kb + c * 16);
  }
}

// ---- write staged regs to LDS (linear slots; ds_write_b128)
__device__ __forceinline__ void write_lds(int tid, const u32x4 r[6],
                                          unsigned char* __restrict__ buf)
{
  #pragma unroll
  for (int q = 0; q < 6; ++q) {
    const int slot = q * 512 + tid;
    *(u32x4*)(buf + slot * 16) = r[q];
  }
}

// ---- one K=64 step (2 x K=32 MFMA) for one gram (R6 verbatim)
__device__ __forceinline__ void gram_pass(
    const unsigned char* __restrict__ A, const unsigned char* __restrict__ B,
    int wr, int wc, int lr, int g, f32x4 acc[6][3])
{
  #pragma unroll
  for (int kk = 0; kk < 2; ++kk) {
    long long a[6], b[3];
    #pragma unroll
    for (int m = 0; m < 6; ++m) {
      const int row = wr * 96 + m * 16 + lr;
      const int off = row * 64 + (((kk * 2 + (g >> 1)) ^ ((row >> 1) & 3)) << 4) + ((g & 1) << 3);
      a[m] = *(const long long*)(A + off);
    }
    #pragma unroll
    for (int n = 0; n < 3; ++n) {
      const int row = wc * 48 + n * 16 + lr;
      const int off = row * 64 + (((kk * 2 + (g >> 1)) ^ ((row >> 1) & 3)) << 4) + ((g & 1) << 3);
      b[n] = *(const long long*)(B + off);
    }
    __builtin_amdgcn_s_setprio(1);
    #pragma unroll
    for (int m = 0; m < 6; ++m)
      #pragma unroll
      for (int n = 0; n < 3; ++n)
        acc[m][n] = __builtin_amdgcn_mfma_f32_16x16x32_fp8_fp8(a[m], b[n], acc[m][n], 0, 0, 0);
    __builtin_amdgcn_s_setprio(0);
  }
}

// ---- main: 192^2 upper-tri tiles, reg-staged ingest (T14), counted-vmcnt pipeline
__global__ __launch_bounds__(512, 2) void gram_kernel(
    const unsigned char* __restrict__ Wb, const unsigned char* __restrict__ Gb,
    const float* __restrict__ sqbW, const float* __restrict__ sqbG,
    const float* __restrict__ scs, const double* __restrict__ ssp,
    float* __restrict__ PU, float* __restrict__ PV, double* __restrict__ PSL)
{
  __shared__ __align__(16) unsigned char lds[2][49152];  // dbuf: AW|BW|AG|BG each
  __shared__ float L[768];   // rowW|rowG|colW|colG reduction arrays
  __shared__ double pred[8], pred2[8];
  __shared__ float sS4;

  // T1: bijective XCD-chunked swizzle (nwg=253: q=31, r=5)
  const int orig = blockIdx.x;
  const int xcd = orig & 7;
  const int idx = orig >> 3;
  const int swz = (xcd < 5 ? xcd * 32 : 5 * 32 + (xcd - 5) * 31) + idx;

  // decode upper-triangular tile index: 0 <= bi <= bj < 22
  int t = swz;
  int bi = 0;
  while (t >= NT - bi) { t -= NT - bi; ++bi; }
  const int bj = bi + t;
  const bool offdiag = (bi != bj);

  const int tid = threadIdx.x;
  const int lane = tid & 63;
  const int wid = tid >> 6;
  const int wr = wid >> 2;      // 0..1  (96-row half)
  const int wc = wid & 3;       // 0..3  (48-col quarter)
  const int i0 = bi * TS;
  const int j0 = bj * TS;
  const int g = lane >> 4;
  const int lr = lane & 15;

  f32x4 accW[6][3], accG[6][3];
  #pragma unroll
  for (int m = 0; m < 6; ++m)
    #pragma unroll
    for (int n = 0; n < 3; ++n) { accW[m][n] = (f32x4)0.0f; accG[m][n] = (f32x4)0.0f; }

  // ---- K-loop: reg-staged double-buffer, ONE lgkm-only barrier per step.
  // Loads for step st+1 are issued before compute of step st; the compiler
  // emits a counted vmcnt before the next write_lds — flight hides under MFMAs.
  u32x4 rA[6], rB[6];
  issue_loads(Wb, Gb, i0, j0, 0, tid, rA);

  #pragma unroll
  for (int st2 = 0; st2 < 4; ++st2) {
    const int st = st2 * 2;
    // even step: regs rA -> lds[0]
    write_lds(tid, rA, lds[0]);                      // auto vmcnt wait for rA only
    issue_loads(Wb, Gb, i0, j0, st + 1, tid, rB);    // st+1 <= 7 always
    __builtin_amdgcn_sched_barrier(0);
    BAR_LGKM();                                      // no vmcnt drain: rB stays in flight
    gram_pass(lds[0], lds[0] + 12288, wr, wc, lr, g, accW);
    gram_pass(lds[0] + 24576, lds[0] + 36864, wr, wc, lr, g, accG);
    // odd step: regs rB -> lds[1]  (WAR on lds[1] protected by this step's barrier)
    write_lds(tid, rB, lds[1]);
    if (st + 2 < 8) issue_loads(Wb, Gb, i0, j0, st + 2, tid, rA);
    __builtin_amdgcn_sched_barrier(0);
    BAR_LGKM();
    gram_pass(lds[1], lds[1] + 12288, wr, wc, lr, g, accW);
    gram_pass(lds[1] + 24576, lds[1] + 36864, wr, wc, lr, g, accG);
  }
  __syncthreads();

  // ---- folded bwk: bandwidth scale computed redundantly per block ----
  {
    float cs = 0.f;
    #pragma unroll 8
    for (int p = 0; p < 32; ++p) cs += scs[p * 512 + tid];
    double p1 = (double)cs * (double)cs;
    double p2 = (tid < 256) ? ssp[tid] : 0.0;
    #pragma unroll
    for (int off = 32; off > 0; off >>= 1) {
      p1 += __shfl_xor(p1, off);
      p2 += __shfl_xor(p2, off);
    }
    if (lane == 0) { pred[wid] = p1; pred2[wid] = p2; }
    __syncthreads();
    if (tid == 0) {
      double s2 = 0.0, ss = 0.0;
      #pragma unroll
      for (int k = 0; k < 8; ++k) { s2 += pred[k]; ss += pred2[k]; }
      double sum_d2 = 2.0 * 8192.0 * ss - 2.0 * s2;
      double bw = sum_d2 / (8192.0 * 8191.0) / 4.0;
      sS4 = (float)(1.4426950408889634 / (bw * 16.0));
    }
    __syncthreads();
  }
  const float s4 = sS4;

  // zero ALL 768 reduction slots (512 threads: two passes)
  L[tid] = 0.f;
  if (tid < 256) L[512 + tid] = 0.f;

  // ---- epilogue: kernel values (f32, fexp2 — validated R11) ----
  float rjW[3], rjG[3], mjf[3];
  #pragma unroll
  for (int n = 0; n < 3; ++n) {
    const int j = j0 + wc * 48 + n * 16 + lr;
    rjW[n] = sqbW[j]; rjG[n] = sqbG[j];
    mjf[n] = (j < NROW) ? 1.f : 0.f;
  }

  float csW[3] = {0.f, 0.f, 0.f}, csG[3] = {0.f, 0.f, 0.f};
  float rsW[6][4], rsG[6][4];
  float p_loc = 0.f;

  #pragma unroll
  for (int m = 0; m < 6; ++m) {
    const int ib = i0 + wr * 96 + m * 16 + g * 4;
    float riW[4], riG[4], mif[4];
    #pragma unroll
    for (int e = 0; e < 4; ++e) {
      riW[e] = sqbW[ib + e]; riG[e] = sqbG[ib + e];
      mif[e] = (ib + e < NROW) ? 1.f : 0.f;
    }
    #pragma unroll
    for (int e = 0; e < 4; ++e) { rsW[m][e] = 0.f; rsG[m][e] = 0.f; }
    #pragma unroll
    for (int n = 0; n < 3; ++n) {
      #pragma unroll
      for (int e = 0; e < 4; ++e) {
        const float mk = mif[e] * mjf[n];
        float d2w = fmaxf(riW[e] + rjW[n] - 2.f * accW[m][n][e], 0.f);
        float yw = fexp2(-d2w * s4);
        float yw2 = yw * yw, yw4 = yw2 * yw2, yw8 = yw4 * yw4, yw16 = yw8 * yw8;
        float kw = (yw + yw2 + yw4 + yw8 + yw16) * mk;
        float d2g = fmaxf(riG[e] + rjG[n] - 2.f * accG[m][n][e], 0.f);
        float yg = fexp2(-d2g * s4);
        float yg2 = yg * yg, yg4 = yg2 * yg2, yg8 = yg4 * yg4, yg16 = yg8 * yg8;
        float kg = (yg + yg2 + yg4 + yg8 + yg16) * mk;
        p_loc = fmaf(kw, kg, p_loc);
        rsW[m][e] += kw; rsG[m][e] += kg;
        csW[n] += kw; csG[n] += kg;
      }
    }
  }

  __syncthreads();   // L zeroing visible

  // row sums -> LDS (butterfly over the 16 column-lanes, then 4-way LDS atomic)
  #pragma unroll
  for (int m = 0; m < 6; ++m)
    #pragma unroll
    for (int e = 0; e < 4; ++e) {
      float x = rsW[m][e], y = rsG[m][e];
      x += __shfl_xor(x, 1); x += __shfl_xor(x, 2); x += __shfl_xor(x, 4); x += __shfl_xor(x, 8);
      y += __shfl_xor(y, 1); y += __shfl_xor(y, 2); y += __shfl_xor(y, 4); y += __shfl_xor(y, 8);
      if (lr == 0) {
        const int rloc = wr * 96 + m * 16 + g * 4 + e;   // 0..191
        atomicAdd(&L[rloc], x);
        atomicAdd(&L[192 + rloc], y);
      }
    }

  // col sums -> LDS (butterfly over g-groups, then 2-way LDS atomic)
  if (offdiag) {
    #pragma unroll
    for (int n = 0; n < 3; ++n) {
      float x = csW[n], y = csG[n];
      x += __shfl_xor(x, 16); x += __shfl_xor(x, 32);
      y += __shfl_xor(y, 16); y += __shfl_xor(y, 32);
      if (g == 0) {
        const int cloc = wc * 48 + n * 16 + lr;          // 0..191
        atomicAdd(&L[384 + cloc], x);
        atomicAdd(&L[576 + cloc], y);
      }
    }
  }

  __syncthreads();

  // plain coalesced partial stores (no global atomics)
  if (tid < 192) {
    PU[(bi * NT + bj) * 192 + tid] = L[tid];
    PV[(bi * NT + bj) * 192 + tid] = L[192 + tid];
    if (offdiag) {
      PU[(bj * NT + bi) * 192 + tid] = L[384 + tid];
      PV[(bj * NT + bi) * 192 + tid] = L[576 + tid];
    }
  }

  // P: f32 wave butterfly -> f64 block sum -> one plain store per tile
  #pragma unroll
  for (int off = 32; off > 0; off >>= 1) p_loc += __shfl_xor(p_loc, off);
  if (lane == 0) pred[wid] = (double)p_loc;
  __syncthreads();
  if (tid == 0) {
    double ps = 0.0;
    #pragma unroll
    for (int k = 0; k < 8; ++k) ps += pred[k];
    PSL[swz] = offdiag ? 2.0 * ps : ps;
  }
}

// ---- finalize (single launch): u,v from partials; loss
__global__ __launch_bounds__(1024) void finalize(
    const float* __restrict__ PU, const float* __restrict__ PV,
    const double* __restrict__ PSL, float* __restrict__ out)
{
  __shared__ double r0[1024], r1[1024], r2[1024], r3[1024];
  const int t = threadIdx.x;
  double uv = 0.0, su = 0.0, sv = 0.0, pp = 0.0;
  for (int i = t; i < NPAD; i += 1024) {
    const int b = i / 192, ii = i - b * 192;
    double uu = 0.0, vv = 0.0;
    #pragma unroll
    for (int k = 0; k < NT; ++k) {
      uu += (double)PU[(b * NT + k) * 192 + ii];
      vv += (double)PV[(b * NT + k) * 192 + ii];
    }
    uv += uu * vv; su += uu; sv += vv;
  }
  if (t < 253) pp = PSL[t];
  r0[t] = uv; r1[t] = su; r2[t] = sv; r3[t] = pp;
  __syncthreads();
  for (int k = 512; k > 0; k >>= 1) {
    if (t < k) { r0[t] += r0[t + k]; r1[t] += r1[t + k]; r2[t] += r2[t + k]; r3[t] += r3[t + k]; }
    __syncthreads();
  }
  if (t == 0) {
    const double n = 4096.0;
    double hsic = r3[0] - (2.0 / n) * r0[0] + (r1[0] * r2[0]) / (n * n);
    out[0] = (float)(-hsic / ((n - 1.0) * (n - 1.0)));
  }
}

extern "C" void kernel_launch(void* const* d_in, const int* in_sizes, int n_in,
                              void* d_out, int out_size, void* d_ws, size_t ws_size,
                              hipStream_t stream) {
  const float* W = (const float*)d_in[0];
  const float* G = (const float*)d_in[1];
  char* ws = (char*)d_ws;
  unsigned char* Wb = (unsigned char*)(ws + WB_OFF);
  unsigned char* Gb = (unsigned char*)(ws + GB_OFF);
  float* sqbW = (float*)(ws + SQBW_OFF);
  float* sqbG = (float*)(ws + SQBG_OFF);
  float* scs = (float*)(ws + SCS_OFF);
  double* ssp = (double*)(ws + SSP_OFF);
  float* PU = (float*)(ws + PU_OFF);
  float* PV = (float*)(ws + PV_OFF);
  double* PSL = (double*)(ws + PSL_OFF);

  hipMemsetAsync(ws + ZERO_BEG, 0, ZERO_END - ZERO_BEG, stream);

  prep_rows<<<2112, 256, 0, stream>>>(W, G, Wb, Gb, sqbW, sqbG, ssp, scs);
  gram_kernel<<<253, 512, 0, stream>>>(Wb, Gb, sqbW, sqbG, scs, ssp, PU, PV, PSL);
  finalize<<<1, 1024, 0, stream>>>(PU, PV, PSL, (float*)d_out);
}